// Round 16
// baseline (425.693 us; speedup 1.0000x reference)
//
#include <hip/hip_runtime.h>
#include <cstdint>
#include <cstddef>

// Problem constants
#define Bn 16
#define Sn 2048
#define Hn 1024
#define Nn 2048   // n_examples * mem_len

typedef unsigned short u16;
typedef float  f32x4  __attribute__((ext_vector_type(4)));
typedef int    i32x4  __attribute__((ext_vector_type(4)));
typedef short  s16x8  __attribute__((ext_vector_type(8)));
typedef unsigned char  u8x4  __attribute__((ext_vector_type(4)));
typedef unsigned char  u8x8  __attribute__((ext_vector_type(8)));

// Two-level int8 quantization: x ~ (q1 + q2/128)/16, q1,q2 in [-127,127].
__device__ __forceinline__ void quant2(float x, char& q1, char& q2) {
  float f1 = rintf(x * 16.f);
  f1 = fminf(127.f, fmaxf(-127.f, f1));
  float r = x - f1 * 0.0625f;
  float f2 = rintf(r * 2048.f);
  f2 = fminf(127.f, fmaxf(-127.f, f2));
  q1 = (char)(int)f1;
  q2 = (char)(int)f2;
}

// Single-level i8 x16 (for the gather's mem operand; max err 1/32).
__device__ __forceinline__ char quant1(float x) {
  float f = rintf(x * 16.f);
  f = fminf(127.f, fmaxf(-127.f, f));
  return (char)(int)f;
}

// Stage 16 rows x 64B (one global_load_lds_dwordx4 per lane, LDS dest linear
// base + lane*16). Global source granule XOR-swizzled with (row>>1)&3 so the
// ds_read side (same XOR) is bank-conflict-free (both-sides rule #21).
__device__ __forceinline__ void stage64Bb(const char* gbase, int pitchBytes, void* ldsbase, int lane) {
  const int gsrc = (lane & 3) ^ ((lane >> 3) & 3);   // g ^ ((row_local>>1)&3), row_local = lane>>2
  const char* gp = gbase + (size_t)(lane >> 2) * pitchBytes + gsrc * 16;
  __builtin_amdgcn_global_load_lds(
      (__attribute__((address_space(1))) void*)gp,
      (__attribute__((address_space(3))) void*)ldsbase, 16, 0, 0);
}

// ---------------- prep kernels (batch-chunk local) ----------------

// seq fp32 -> two-level i8, 4 per thread.
__global__ __launch_bounds__(256) void prep_seq_i8(const float* __restrict__ seq,
                                                   char* __restrict__ a1, char* __restrict__ a2) {
  size_t i = (size_t)blockIdx.x * 256 + threadIdx.x;
  float4 v = ((const float4*)seq)[i];
  float x[4] = {v.x, v.y, v.z, v.w};
  u8x4 p1, p2;
#pragma unroll
  for (int j = 0; j < 4; ++j) {
    char q1, q2;
    quant2(x[j], q1, q2);
    p1[j] = (unsigned char)q1;
    p2[j] = (unsigned char)q2;
  }
  ((u8x4*)a1)[i] = p1;
  ((u8x4*)a2)[i] = p2;
}

// Fused memory prep: reads each mem element ONCE (as the [N][H] view), emits
//  bt1[n'][h'] i8 two-level  where flat[h'*2048+n'] = flat[r*1024+c]
//    (n' = (r&1)*1024 + c, h' = r>>1; mask index = 2h'+(n'>>10) = r)
//  memq[n][h]  i8 x16        (natural [N][H] layout, masked; gather operand)
__global__ __launch_bounds__(256) void prep_bt(const float* __restrict__ mem,
                                               const int* __restrict__ mmask,
                                               char* __restrict__ b1o, char* __restrict__ b2o,
                                               char* __restrict__ memq) {
  __shared__ float tile[64][33];
  const int b = blockIdx.z;
  const int r0 = blockIdx.x * 64;   // 32 blocks (n dim)
  const int c0 = blockIdx.y * 32;   // 32 blocks (h dim)
  const int tx = threadIdx.x & 31, ty = threadIdx.x >> 5;   // 32 x 8
  const float* src = mem + (size_t)b * (Nn * Hn);
  const int* mk = mmask + b * Nn;
#pragma unroll
  for (int j = 0; j < 8; ++j) {
    int r = r0 + ty + j * 8;
    float v = src[(size_t)r * Hn + c0 + tx];
    v = mk[r] ? v : 0.f;
    tile[ty + j * 8][tx] = v;
  }
  __syncthreads();
  // memq: natural layout; 4 threads per n-row, 8 i8 each (32B/row region).
  {
    const int nr = threadIdx.x >> 2;          // 0..63 (n local)
    const int hb = (threadIdx.x & 3) * 8;     // 0..24 (h local)
    u8x8 ov;
#pragma unroll
    for (int j = 0; j < 8; ++j) ov[j] = (unsigned char)quant1(tile[nr][hb + j]);
    *(u8x8*)(memq + (size_t)b * Nn * Hn + (size_t)(r0 + nr) * Hn + c0 + hb) = ov;
  }
  // bt1: n' = p*1024 + c0 + cl, h' = r0/2 + q*8 + j; 8 i8 pairs per thread
  {
    const int cl = threadIdx.x & 31;
    const int p  = (threadIdx.x >> 5) & 1;
    const int q  = threadIdx.x >> 6;          // 0..3
    u8x8 o1, o2;
#pragma unroll
    for (int j = 0; j < 8; ++j) {
      char q1, q2;
      quant2(tile[2 * (q * 8 + j) + p][cl], q1, q2);
      o1[j] = (unsigned char)q1;
      o2[j] = (unsigned char)q2;
    }
    size_t o = (size_t)b * Nn * Hn + (size_t)(p * 1024 + c0 + cl) * Hn + (r0 >> 1) + q * 8;
    *(u8x8*)(b1o + o) = o1;
    *(u8x8*)(b2o + o) = o2;
  }
}

// ---------------- GEMM1 (coarse): scores_c = a1.b1/256, i16 x128 + tile-max ----------------
// 128x128 tile, BK=64, 4 waves (2x2). TRI-buffered LDS (3 x 16KB = 48KB,
// 3 blocks/CU), stage(k+2) issued in body k, counted vmcnt(4) entry waits.
// Epilogue additionally emits gtmax[row][tn] = max of this tile's 128
// quantized scores per row (max commutes with the monotone rint/clamp).
__global__ __launch_bounds__(256, 3) void gemm_scores_coarse(
    const char* __restrict__ A1, const char* __restrict__ B1,
    short* __restrict__ C, short* __restrict__ gtmax) {
  __shared__ __align__(16) char ldsm[49152];   // 3 buffers x {A 8KB | B 8KB}
  __shared__ short tmx[2][128];
  const int b = blockIdx.z;
  // XCD-aware remap: each XCD's blocks form an 8(tn) x 4(tm) rectangle.
  const int lid = blockIdx.x + (blockIdx.y << 4);
  const int xcd = lid & 7, idx = lid >> 3;
  const int tn = ((xcd & 1) << 3) | (idx & 7);
  const int tm = ((xcd >> 1) << 2) | (idx >> 3);
  const int tid = threadIdx.x;
  const int w = tid >> 6, l = tid & 63;
  const int wr = w >> 1, wc = w & 1;
  const size_t aOff = (size_t)(b * Sn + tm * 128) * Hn;
  const size_t bOff = (size_t)(b * Nn + tn * 128) * Hn;

  i32x4 acc[4][4] = {};

  const int gRd = ((l >> 4) ^ ((l >> 1) & 3)) * 16;
  const int ao = (wr * 64 + (l & 15)) * 64 + gRd;
  const int bo = (wc * 64 + (l & 15)) * 64 + gRd;

  auto stageStep = [&](int kk, char* buf) {   // 4 loads per lane
    const int kb = kk * 64;
#pragma unroll
    for (int i = 0; i < 2; ++i) {
      const int rb = w * 32 + i * 16;
      const size_t ro = (size_t)rb * Hn + kb;
      stage64Bb(A1 + aOff + ro, Hn, buf + rb * 64, l);
      stage64Bb(B1 + bOff + ro, Hn, buf + 8192 + rb * 64, l);
    }
  };

  stageStep(0, ldsm);
  stageStep(1, ldsm + 16384);

  int cb = 0;
  for (int kk = 0; kk < 16; ++kk) {
    char* cur = ldsm + cb * 16384;
    int sb = cb + 2; if (sb >= 3) sb -= 3;
    if (kk <= 14) asm volatile("s_waitcnt vmcnt(4)" ::: "memory");
    else          asm volatile("s_waitcnt vmcnt(0)" ::: "memory");
    __builtin_amdgcn_s_barrier();
    asm volatile("" ::: "memory");
    __builtin_amdgcn_sched_barrier(0);
    i32x4 bfr[4];
#pragma unroll
    for (int ni = 0; ni < 4; ++ni) bfr[ni] = *(const i32x4*)(cur + 8192 + bo + ni * 1024);
    i32x4 afr[4];
#pragma unroll
    for (int mi = 0; mi < 4; ++mi) afr[mi] = *(const i32x4*)(cur + ao + mi * 1024);
    if (kk + 2 < 16) stageStep(kk + 2, ldsm + sb * 16384);
    __builtin_amdgcn_s_setprio(1);
#pragma unroll
    for (int mi = 0; mi < 4; ++mi)
#pragma unroll
      for (int ni = 0; ni < 4; ++ni)
        acc[mi][ni] = __builtin_amdgcn_mfma_i32_16x16x64_i8(afr[mi], bfr[ni], acc[mi][ni], 0, 0, 0);
    __builtin_amdgcn_s_setprio(0);
    cb = (cb + 1 == 3) ? 0 : cb + 1;
  }
  // coarse_fixed = acc/2 (= coarse_score * 128), i16.
  const int r0 = tm * 128 + wr * 64 + (l >> 4) * 4;
  const int c0 = tn * 128 + wc * 64 + (l & 15);
#pragma unroll
  for (int mi = 0; mi < 4; ++mi)
#pragma unroll
    for (int ni = 0; ni < 4; ++ni) {
      size_t base = (size_t)(b * Sn + r0 + mi * 16) * Nn + c0 + ni * 16;
#pragma unroll
      for (int j = 0; j < 4; ++j) {
        int s = (int)rintf((float)acc[mi][ni][j] * 0.5f);
        s = s > 32767 ? 32767 : (s < -32767 ? -32767 : s);
        C[base + (size_t)j * Nn] = (short)s;
      }
    }
  // Per-row tile max over this block's 128 cols.
  int rmax[4][4];
#pragma unroll
  for (int mi = 0; mi < 4; ++mi)
#pragma unroll
    for (int j = 0; j < 4; ++j) {
      int mv = acc[mi][0][j];
#pragma unroll
      for (int ni = 1; ni < 4; ++ni) mv = max(mv, acc[mi][ni][j]);
      rmax[mi][j] = mv;
    }
  // reduce over the 16 column-lanes (l&15); xor o<16 keeps l>>4 fixed.
#pragma unroll
  for (int o = 1; o < 16; o <<= 1)
#pragma unroll
    for (int mi = 0; mi < 4; ++mi)
#pragma unroll
      for (int j = 0; j < 4; ++j)
        rmax[mi][j] = max(rmax[mi][j], __shfl_xor(rmax[mi][j], o));
  if ((l & 15) == 0) {
#pragma unroll
    for (int mi = 0; mi < 4; ++mi)
#pragma unroll
      for (int j = 0; j < 4; ++j) {
        int s = (int)rintf((float)rmax[mi][j] * 0.5f);
        s = s > 32767 ? 32767 : (s < -32767 ? -32767 : s);
        tmx[wc][wr * 64 + mi * 16 + (l >> 4) * 4 + j] = (short)s;
      }
  }
  __syncthreads();
  if (tid < 128) {
    short mA = tmx[0][tid], mB = tmx[1][tid];
    gtmax[(size_t)(b * Sn + tm * 128 + tid) * 16 + tn] = mA > mB ? mA : mB;
  }
}

// ---------------- Fused softmax + refinement + sparse gather + residual ----------------
// One 256-thread block per row. Tile-max prescreen: only tiles with
// tmax >= rowmax-11 can contain candidates (identical candidate set & order
// to the full scan -> bit-identical output). Candidates refined with the
// exact cross term; p8 = rint(127*p); integer gather; residual from a1/a2.
__global__ __launch_bounds__(256) void softmax_attn(
    const short* __restrict__ sc,    // i16 coarse scores x128, [BC*Sn][Nn]
    const short* __restrict__ tmax,  // i16 tile maxes, [BC*Sn][16]
    const char* __restrict__ memq,   // i8 mem x16, [BC][Nn][Hn]
    const char* __restrict__ B1q, const char* __restrict__ B2q,  // bt1 two-level
    const char* __restrict__ A1q, const char* __restrict__ A2q,
    float* __restrict__ out) {
  __shared__ short sh16[16];
  __shared__ int wtot[4];
  __shared__ int ncand_s;
  __shared__ unsigned short sidx[64];
  __shared__ int scand[64];
  __shared__ int scross[64];
  __shared__ unsigned char sp[64];
  const size_t row = blockIdx.x;
  const int b = (int)(row >> 11);          // Sn = 2048 rows per batch
  const int t = threadIdx.x;
  const int w = t >> 6, l = t & 63;
  if (t < 16) sh16[t] = tmax[row * 16 + t];
  if (t == 0) ncand_s = 0;
  __syncthreads();
  int mc = -32768;
#pragma unroll
  for (int i = 0; i < 16; ++i) mc = max(mc, (int)sh16[i]);
  const int thresh = mc - 1408;            // 11 * 128
  // candidate extraction over qualifying tiles only (ascending n order).
  for (int ti = 0; ti < 16; ++ti) {
    if ((int)sh16[ti] < thresh) continue;
    int sval = 0, flag = 0;
    if (t < 128) {
      sval = (int)sc[row * (size_t)Nn + ti * 128 + t];
      flag = (sval >= thresh) ? 1 : 0;
    }
    int incl = flag;
    for (int o = 1; o < 64; o <<= 1) {
      int xv = __shfl_up(incl, o);
      if (l >= o) incl += xv;
    }
    if (l == 63) wtot[w] = incl;
    __syncthreads();
    const int base2 = ncand_s;
    int basew = 0;
#pragma unroll
    for (int wq = 0; wq < 4; ++wq) if (wq < w) basew += wtot[wq];
    const int pos = base2 + basew + incl - flag;
    if (flag && pos < 64) { sidx[pos] = (unsigned short)(ti * 128 + t); scand[pos] = sval; }
    __syncthreads();
    if (t == 0) {
      int nn = base2 + wtot[0] + wtot[1] + wtot[2] + wtot[3];
      ncand_s = nn > 64 ? 64 : nn;
    }
    __syncthreads();
  }
  const int total = ncand_s;
  // Refinement: wave w handles candidate k0+w; lane l covers k-slice l*16..+15.
  const i32x4 a1s = *(const i32x4*)(A1q + row * (size_t)Hn + l * 16);
  const i32x4 a2s = *(const i32x4*)(A2q + row * (size_t)Hn + l * 16);
  for (int k0 = 0; k0 < total; k0 += 4) {
    const int k = k0 + w;
    int cross = 0;
    if (k < total) {
      const size_t nb = ((size_t)b * Nn + sidx[k]) * Hn + l * 16;
      const i32x4 b1v = *(const i32x4*)(B1q + nb);
      const i32x4 b2v = *(const i32x4*)(B2q + nb);
#pragma unroll
      for (int r = 0; r < 4; ++r)
#pragma unroll
        for (int s8 = 0; s8 < 4; ++s8) {
          const int sh = s8 * 8;
          cross += (int)(char)(a1s[r] >> sh) * (int)(char)(b2v[r] >> sh)
                 + (int)(char)(a2s[r] >> sh) * (int)(char)(b1v[r] >> sh);
        }
    }
    for (int o = 32; o > 0; o >>= 1) cross += __shfl_xor(cross, o);
    if (l == 0 && k < total) scross[k] = cross;
  }
  __syncthreads();
  // p8 over refined candidates
  if (t < total) {
    float mref = -1e30f;
    for (int k = 0; k < total; ++k) {
      float f = (float)scand[k] * 0.0078125f + (float)scross[k] * (1.f / 32768.f);
      mref = fmaxf(mref, f);
    }
    float s = 0.f;
    for (int k = 0; k < total; ++k) {
      float f = (float)scand[k] * 0.0078125f + (float)scross[k] * (1.f / 32768.f);
      s += __expf(f - mref);
    }
    const float fme = (float)scand[t] * 0.0078125f + (float)scross[t] * (1.f / 32768.f);
    sp[t] = (unsigned char)(int)rintf(127.f * __expf(fme - mref) / s);
  }
  __syncthreads();
  // Cooperative gather: per nonzero candidate all 256 threads read 4 i8.
  const char* mq = memq + (size_t)b * (Nn * Hn);
  int a0 = 0, a1v = 0, a2v = 0, a3 = 0;
  for (int k = 0; k < total; ++k) {
    const int pw = sp[k];
    if (!pw) continue;
    const int n = sidx[k];
    const int wv = *(const int*)(mq + (size_t)n * Hn + (t << 2));
    a0 += pw * (int)(char)(wv);
    a1v += pw * (int)(char)(wv >> 8);
    a2v += pw * (int)(char)(wv >> 16);
    a3 += pw * (int)(char)(wv >> 24);
  }
  // Residual from a1/a2 (seq ~ a1/16 + a2/2048) + acc/(127*16).
  const size_t obase = row * Hn + (size_t)(t << 2);
  const int w1 = *(const int*)(A1q + obase);
  const int w2 = *(const int*)(A2q + obase);
  const float scl = 1.f / 2032.f;
  float4 o;
  o.x = (float)(char)(w1)       * 0.0625f + (float)(char)(w2)       * (1.f / 2048.f) + (float)a0 * scl;
  o.y = (float)(char)(w1 >> 8)  * 0.0625f + (float)(char)(w2 >> 8)  * (1.f / 2048.f) + (float)a1v * scl;
  o.z = (float)(char)(w1 >> 16) * 0.0625f + (float)(char)(w2 >> 16) * (1.f / 2048.f) + (float)a2v * scl;
  o.w = (float)(char)(w1 >> 24) * 0.0625f + (float)(char)(w2 >> 24) * (1.f / 2048.f) + (float)a3 * scl;
  *(float4*)(out + obase) = o;
}

// Distinctive fill if ws is too small: absmax ~12345 tells us it was this guard.
__global__ void ws_fail(float* out) {
  size_t i = (size_t)blockIdx.x * blockDim.x + threadIdx.x;
  size_t stride = (size_t)gridDim.x * blockDim.x;
  for (; i < (size_t)Bn * Sn * Hn; i += stride) out[i] = 12345.0f;
}

extern "C" void kernel_launch(void* const* d_in, const int* in_sizes, int n_in,
                              void* d_out, int out_size, void* d_ws, size_t ws_size,
                              hipStream_t stream) {
  const float* seq = (const float*)d_in[0];
  // d_in[1] (attention_mask) is unused by the reference
  const float* mem = (const float*)d_in[2];
  const int* mmask = (const int*)d_in[3];
  float* out = (float*)d_out;

  // Per-batch: a1,a2,b1,b2 (4x2 MiB) + memq (2 MiB) + scores i16 (8 MiB)
  //            + tmax (64 KiB) = 18.0625 MiB
  const size_t MiB = 1024 * 1024;
  const size_t perB = 18 * MiB + 64 * 1024;
  int BC = 16;
  while (BC > 1 && (size_t)BC * perB > ws_size) BC >>= 1;
  if ((size_t)BC * perB > ws_size) {
    ws_fail<<<2048, 256, 0, stream>>>(out);
    return;
  }

  char* ws = (char*)d_ws;
  const size_t SEG8 = (size_t)BC * Sn * Hn;       // BC * 2 MiB
  char* a1 = ws;
  char* a2 = ws + SEG8;
  char* b1 = ws + 2 * SEG8;
  char* b2 = ws + 3 * SEG8;
  char* memq = ws + 4 * SEG8;                     // 1 SEG8
  short* scores = (short*)(ws + 5 * SEG8);        // 4 SEG8 (BC x 8 MiB)
  short* tmaxb = (short*)(ws + 9 * SEG8);         // BC x 64 KiB

  for (int b0 = 0; b0 < Bn; b0 += BC) {
    const float* seqb = seq + (size_t)b0 * Sn * Hn;
    const float* memb = mem + (size_t)b0 * Nn * Hn;
    const int* mkb = mmask + (size_t)b0 * Nn;
    float* outb = out + (size_t)b0 * Sn * Hn;

    prep_seq_i8<<<dim3(BC * Sn * Hn / 4 / 256), 256, 0, stream>>>(seqb, a1, a2);
    prep_bt<<<dim3(Nn / 64, Hn / 32, BC), 256, 0, stream>>>(memb, mkb, b1, b2, memq);
    gemm_scores_coarse<<<dim3(Nn / 128, Sn / 128, BC), 256, 0, stream>>>(a1, b1, scores, tmaxb);
    softmax_attn<<<dim3(BC * Sn), 256, 0, stream>>>(scores, tmaxb, memq, b1, b2, a1, a2, outb);
  }
}

// Round 19
// 362.746 us; speedup vs baseline: 1.1735x; 1.1735x over previous
//
#include <hip/hip_runtime.h>
#include <cstdint>
#include <cstddef>

// Problem constants
#define Bn 16
#define Sn 2048
#define Hn 1024
#define Nn 2048   // n_examples * mem_len

typedef unsigned short u16;
typedef float  f32x4  __attribute__((ext_vector_type(4)));
typedef int    i32x4  __attribute__((ext_vector_type(4)));
typedef short  s16x8  __attribute__((ext_vector_type(8)));
typedef unsigned char  u8x4  __attribute__((ext_vector_type(4)));
typedef unsigned char  u8x8  __attribute__((ext_vector_type(8)));

// Two-level int8 quantization: x ~ (q1 + q2/128)/16, q1,q2 in [-127,127].
__device__ __forceinline__ void quant2(float x, char& q1, char& q2) {
  float f1 = rintf(x * 16.f);
  f1 = fminf(127.f, fmaxf(-127.f, f1));
  float r = x - f1 * 0.0625f;
  float f2 = rintf(r * 2048.f);
  f2 = fminf(127.f, fmaxf(-127.f, f2));
  q1 = (char)(int)f1;
  q2 = (char)(int)f2;
}

// Single-level i8 x16 (for the gather's mem operand; max err 1/32).
__device__ __forceinline__ char quant1(float x) {
  float f = rintf(x * 16.f);
  f = fminf(127.f, fmaxf(-127.f, f));
  return (char)(int)f;
}

// Stage 16 rows x 64B (one global_load_lds_dwordx4 per lane, LDS dest linear
// base + lane*16). Global source granule XOR-swizzled with (row>>1)&3 so the
// ds_read side (same XOR) is bank-conflict-free (both-sides rule #21).
__device__ __forceinline__ void stage64Bb(const char* gbase, int pitchBytes, void* ldsbase, int lane) {
  const int gsrc = (lane & 3) ^ ((lane >> 3) & 3);   // g ^ ((row_local>>1)&3), row_local = lane>>2
  const char* gp = gbase + (size_t)(lane >> 2) * pitchBytes + gsrc * 16;
  __builtin_amdgcn_global_load_lds(
      (__attribute__((address_space(1))) void*)gp,
      (__attribute__((address_space(3))) void*)ldsbase, 16, 0, 0);
}

// ---------------- prep kernels (batch-chunk local) ----------------

// seq fp32 -> two-level i8, 4 per thread.
__global__ __launch_bounds__(256) void prep_seq_i8(const float* __restrict__ seq,
                                                   char* __restrict__ a1, char* __restrict__ a2) {
  size_t i = (size_t)blockIdx.x * 256 + threadIdx.x;
  float4 v = ((const float4*)seq)[i];
  float x[4] = {v.x, v.y, v.z, v.w};
  u8x4 p1, p2;
#pragma unroll
  for (int j = 0; j < 4; ++j) {
    char q1, q2;
    quant2(x[j], q1, q2);
    p1[j] = (unsigned char)q1;
    p2[j] = (unsigned char)q2;
  }
  ((u8x4*)a1)[i] = p1;
  ((u8x4*)a2)[i] = p2;
}

// Fused memory prep: reads each mem element ONCE (as the [N][H] view), emits
//  bt1[n'][h'] i8 two-level  where flat[h'*2048+n'] = flat[r*1024+c]
//    (n' = (r&1)*1024 + c, h' = r>>1; mask index = 2h'+(n'>>10) = r)
//  memq[n][h]  i8 x16        (natural [N][H] layout, masked; gather operand)
__global__ __launch_bounds__(256) void prep_bt(const float* __restrict__ mem,
                                               const int* __restrict__ mmask,
                                               char* __restrict__ b1o, char* __restrict__ b2o,
                                               char* __restrict__ memq) {
  __shared__ float tile[64][33];
  const int b = blockIdx.z;
  const int r0 = blockIdx.x * 64;   // 32 blocks (n dim)
  const int c0 = blockIdx.y * 32;   // 32 blocks (h dim)
  const int tx = threadIdx.x & 31, ty = threadIdx.x >> 5;   // 32 x 8
  const float* src = mem + (size_t)b * (Nn * Hn);
  const int* mk = mmask + b * Nn;
#pragma unroll
  for (int j = 0; j < 8; ++j) {
    int r = r0 + ty + j * 8;
    float v = src[(size_t)r * Hn + c0 + tx];
    v = mk[r] ? v : 0.f;
    tile[ty + j * 8][tx] = v;
  }
  __syncthreads();
  // memq: natural layout; 4 threads per n-row, 8 i8 each (32B/row region).
  {
    const int nr = threadIdx.x >> 2;          // 0..63 (n local)
    const int hb = (threadIdx.x & 3) * 8;     // 0..24 (h local)
    u8x8 ov;
#pragma unroll
    for (int j = 0; j < 8; ++j) ov[j] = (unsigned char)quant1(tile[nr][hb + j]);
    *(u8x8*)(memq + (size_t)b * Nn * Hn + (size_t)(r0 + nr) * Hn + c0 + hb) = ov;
  }
  // bt1: n' = p*1024 + c0 + cl, h' = r0/2 + q*8 + j; 8 i8 pairs per thread
  {
    const int cl = threadIdx.x & 31;
    const int p  = (threadIdx.x >> 5) & 1;
    const int q  = threadIdx.x >> 6;          // 0..3
    u8x8 o1, o2;
#pragma unroll
    for (int j = 0; j < 8; ++j) {
      char q1, q2;
      quant2(tile[2 * (q * 8 + j) + p][cl], q1, q2);
      o1[j] = (unsigned char)q1;
      o2[j] = (unsigned char)q2;
    }
    size_t o = (size_t)b * Nn * Hn + (size_t)(p * 1024 + c0 + cl) * Hn + (r0 >> 1) + q * 8;
    *(u8x8*)(b1o + o) = o1;
    *(u8x8*)(b2o + o) = o2;
  }
}

// ---------------- GEMM1 (coarse): scores_c = a1.b1/256, i16 x128 ----------------
// 128x128 tile, BK=64, 4 waves (2x2). TRI-buffered LDS (3 x 16KB = 48KB,
// 3 blocks/CU), stage(k+2) issued in body k, counted vmcnt(4) entry waits
// (proven pattern from the R13 attention GEMM). 16 MFMA/K-tile.
__global__ __launch_bounds__(256, 3) void gemm_scores_coarse(
    const char* __restrict__ A1, const char* __restrict__ B1,
    short* __restrict__ C) {
  __shared__ __align__(16) char ldsm[49152];   // 3 buffers x {A 8KB | B 8KB}
  const int b = blockIdx.z;
  // XCD-aware remap: each XCD's blocks form an 8(tn) x 4(tm) rectangle.
  const int lid = blockIdx.x + (blockIdx.y << 4);
  const int xcd = lid & 7, idx = lid >> 3;
  const int tn = ((xcd & 1) << 3) | (idx & 7);
  const int tm = ((xcd >> 1) << 2) | (idx >> 3);
  const int tid = threadIdx.x;
  const int w = tid >> 6, l = tid & 63;
  const int wr = w >> 1, wc = w & 1;
  const size_t aOff = (size_t)(b * Sn + tm * 128) * Hn;
  const size_t bOff = (size_t)(b * Nn + tn * 128) * Hn;

  i32x4 acc[4][4] = {};

  const int gRd = ((l >> 4) ^ ((l >> 1) & 3)) * 16;
  const int ao = (wr * 64 + (l & 15)) * 64 + gRd;
  const int bo = (wc * 64 + (l & 15)) * 64 + gRd;

  auto stageStep = [&](int kk, char* buf) {   // 4 loads per lane
    const int kb = kk * 64;
#pragma unroll
    for (int i = 0; i < 2; ++i) {
      const int rb = w * 32 + i * 16;
      const size_t ro = (size_t)rb * Hn + kb;
      stage64Bb(A1 + aOff + ro, Hn, buf + rb * 64, l);
      stage64Bb(B1 + bOff + ro, Hn, buf + 8192 + rb * 64, l);
    }
  };

  stageStep(0, ldsm);
  stageStep(1, ldsm + 16384);

  int cb = 0;
  for (int kk = 0; kk < 16; ++kk) {
    char* cur = ldsm + cb * 16384;
    int sb = cb + 2; if (sb >= 3) sb -= 3;
    if (kk <= 14) asm volatile("s_waitcnt vmcnt(4)" ::: "memory");
    else          asm volatile("s_waitcnt vmcnt(0)" ::: "memory");
    __builtin_amdgcn_s_barrier();
    asm volatile("" ::: "memory");
    __builtin_amdgcn_sched_barrier(0);
    i32x4 bfr[4];
#pragma unroll
    for (int ni = 0; ni < 4; ++ni) bfr[ni] = *(const i32x4*)(cur + 8192 + bo + ni * 1024);
    i32x4 afr[4];
#pragma unroll
    for (int mi = 0; mi < 4; ++mi) afr[mi] = *(const i32x4*)(cur + ao + mi * 1024);
    if (kk + 2 < 16) stageStep(kk + 2, ldsm + sb * 16384);
    __builtin_amdgcn_s_setprio(1);
#pragma unroll
    for (int mi = 0; mi < 4; ++mi)
#pragma unroll
      for (int ni = 0; ni < 4; ++ni)
        acc[mi][ni] = __builtin_amdgcn_mfma_i32_16x16x64_i8(afr[mi], bfr[ni], acc[mi][ni], 0, 0, 0);
    __builtin_amdgcn_s_setprio(0);
    cb = (cb + 1 == 3) ? 0 : cb + 1;
  }
  // coarse_fixed = acc/2 (= coarse_score * 128), i16.
  const int r0 = tm * 128 + wr * 64 + (l >> 4) * 4;
  const int c0 = tn * 128 + wc * 64 + (l & 15);
#pragma unroll
  for (int mi = 0; mi < 4; ++mi)
#pragma unroll
    for (int ni = 0; ni < 4; ++ni) {
      size_t base = (size_t)(b * Sn + r0 + mi * 16) * Nn + c0 + ni * 16;
#pragma unroll
      for (int j = 0; j < 4; ++j) {
        int s = (int)rintf((float)acc[mi][ni][j] * 0.5f);
        s = s > 32767 ? 32767 : (s < -32767 ? -32767 : s);
        C[base + (size_t)j * Nn] = (short)s;
      }
    }
}

// ---------------- Fused softmax + refinement + sparse gather + residual ----------------
// One 256-thread block per output row. Coarse scores (err std ~0.8) select
// candidates within 11 of the coarse max (expected ~2, cap 64). Candidates
// are refined with the exact cross term (a1.b2 + a2.b1)/32768 -- same error
// class as the old full two-level scores. Softmax over refined candidates
// (excluded tail contributes <= e^-8 to the denominator); p8 = rint(127*p);
// integer gather of memq rows where p8 != 0; residual from a1/a2.
__global__ __launch_bounds__(256) void softmax_attn(
    const short* __restrict__ sc,    // i16 coarse scores x128, [BC*Sn][Nn]
    const char* __restrict__ memq,   // i8 mem x16, [BC][Nn][Hn]
    const char* __restrict__ B1q, const char* __restrict__ B2q,  // bt1 two-level
    const char* __restrict__ A1q, const char* __restrict__ A2q,
    float* __restrict__ out) {
  __shared__ int redi[4];
  __shared__ int wtot[4];
  __shared__ unsigned short sidx[64];
  __shared__ int scand[64];
  __shared__ int scross[64];
  __shared__ unsigned char sp[64];
  const size_t row = blockIdx.x;
  const int b = (int)(row >> 11);          // Sn = 2048 rows per batch
  const int t = threadIdx.x;
  const int w = t >> 6, l = t & 63;
  s16x8 v = ((const s16x8*)(sc + row * Nn))[t];
  // coarse row max
  int mymax = (int)v[0];
#pragma unroll
  for (int j = 1; j < 8; ++j) mymax = max(mymax, (int)v[j]);
  for (int o = 32; o > 0; o >>= 1) mymax = max(mymax, __shfl_xor(mymax, o));
  if (l == 0) redi[w] = mymax;
  __syncthreads();
  const int mc = max(max(redi[0], redi[1]), max(redi[2], redi[3]));
  const int thresh = mc - 1408;            // 11 * 128
  // count + deterministic exclusive scan over 256 threads
  int cnt = 0;
#pragma unroll
  for (int j = 0; j < 8; ++j) cnt += ((int)v[j] >= thresh);
  int incl = cnt;
  for (int o = 1; o < 64; o <<= 1) {
    int xv = __shfl_up(incl, o);
    if (l >= o) incl += xv;
  }
  if (l == 63) wtot[w] = incl;
  __syncthreads();
  int base = 0;
#pragma unroll
  for (int wq = 0; wq < 4; ++wq) if (wq < w) base += wtot[wq];
  int pos = base + incl - cnt;
#pragma unroll
  for (int j = 0; j < 8; ++j)
    if ((int)v[j] >= thresh) {
      if (pos < 64) { sidx[pos] = (unsigned short)(t * 8 + j); scand[pos] = (int)v[j]; }
      pos++;
    }
  __syncthreads();
  int total = wtot[0] + wtot[1] + wtot[2] + wtot[3];
  if (total > 64) total = 64;
  // Refinement: wave w handles candidate k0+w; lane l covers k-slice l*16..+15.
  const i32x4 a1s = *(const i32x4*)(A1q + row * (size_t)Hn + l * 16);
  const i32x4 a2s = *(const i32x4*)(A2q + row * (size_t)Hn + l * 16);
  for (int k0 = 0; k0 < total; k0 += 4) {
    const int k = k0 + w;
    int cross = 0;
    if (k < total) {
      const size_t nb = ((size_t)b * Nn + sidx[k]) * Hn + l * 16;
      const i32x4 b1v = *(const i32x4*)(B1q + nb);
      const i32x4 b2v = *(const i32x4*)(B2q + nb);
#pragma unroll
      for (int r = 0; r < 4; ++r)
#pragma unroll
        for (int s8 = 0; s8 < 4; ++s8) {
          const int sh = s8 * 8;
          cross += (int)(char)(a1s[r] >> sh) * (int)(char)(b2v[r] >> sh)
                 + (int)(char)(a2s[r] >> sh) * (int)(char)(b1v[r] >> sh);
        }
    }
    for (int o = 32; o > 0; o >>= 1) cross += __shfl_xor(cross, o);
    if (l == 0 && k < total) scross[k] = cross;
  }
  __syncthreads();
  // p8 over refined candidates (threads 0..total-1 write; all compute m,s)
  if (t < total) {
    float mref = -1e30f;
    for (int k = 0; k < total; ++k) {
      float f = (float)scand[k] * 0.0078125f + (float)scross[k] * (1.f / 32768.f);
      mref = fmaxf(mref, f);
    }
    float s = 0.f;
    for (int k = 0; k < total; ++k) {
      float f = (float)scand[k] * 0.0078125f + (float)scross[k] * (1.f / 32768.f);
      s += __expf(f - mref);
    }
    const float fme = (float)scand[t] * 0.0078125f + (float)scross[t] * (1.f / 32768.f);
    sp[t] = (unsigned char)(int)rintf(127.f * __expf(fme - mref) / s);
  }
  __syncthreads();
  // Cooperative gather: per nonzero candidate all 256 threads read 4 i8.
  const char* mq = memq + (size_t)b * (Nn * Hn);
  int a0 = 0, a1v = 0, a2v = 0, a3 = 0;
  for (int k = 0; k < total; ++k) {
    const int pw = sp[k];
    if (!pw) continue;
    const int n = sidx[k];
    const int wv = *(const int*)(mq + (size_t)n * Hn + (t << 2));
    a0 += pw * (int)(char)(wv);
    a1v += pw * (int)(char)(wv >> 8);
    a2v += pw * (int)(char)(wv >> 16);
    a3 += pw * (int)(char)(wv >> 24);
  }
  // Residual from a1/a2 (seq ~ a1/16 + a2/2048) + acc/(127*16).
  const size_t obase = row * Hn + (size_t)(t << 2);
  const int w1 = *(const int*)(A1q + obase);
  const int w2 = *(const int*)(A2q + obase);
  const float scl = 1.f / 2032.f;
  float4 o;
  o.x = (float)(char)(w1)       * 0.0625f + (float)(char)(w2)       * (1.f / 2048.f) + (float)a0 * scl;
  o.y = (float)(char)(w1 >> 8)  * 0.0625f + (float)(char)(w2 >> 8)  * (1.f / 2048.f) + (float)a1v * scl;
  o.z = (float)(char)(w1 >> 16) * 0.0625f + (float)(char)(w2 >> 16) * (1.f / 2048.f) + (float)a2v * scl;
  o.w = (float)(char)(w1 >> 24) * 0.0625f + (float)(char)(w2 >> 24) * (1.f / 2048.f) + (float)a3 * scl;
  *(float4*)(out + obase) = o;
}

// Distinctive fill if ws is too small: absmax ~12345 tells us it was this guard.
__global__ void ws_fail(float* out) {
  size_t i = (size_t)blockIdx.x * blockDim.x + threadIdx.x;
  size_t stride = (size_t)gridDim.x * blockDim.x;
  for (; i < (size_t)Bn * Sn * Hn; i += stride) out[i] = 12345.0f;
}

extern "C" void kernel_launch(void* const* d_in, const int* in_sizes, int n_in,
                              void* d_out, int out_size, void* d_ws, size_t ws_size,
                              hipStream_t stream) {
  const float* seq = (const float*)d_in[0];
  // d_in[1] (attention_mask) is unused by the reference
  const float* mem = (const float*)d_in[2];
  const int* mmask = (const int*)d_in[3];
  float* out = (float*)d_out;

  // Per-batch: a1,a2,b1,b2 (4x2 MiB) + memq (2 MiB) + scores i16 (8 MiB) = 18 MiB
  const size_t MiB = 1024 * 1024;
  const size_t perB = 18 * MiB;
  int BC = 16;
  while (BC > 1 && (size_t)BC * perB > ws_size) BC >>= 1;
  if ((size_t)BC * perB > ws_size) {
    ws_fail<<<2048, 256, 0, stream>>>(out);
    return;
  }

  char* ws = (char*)d_ws;
  const size_t SEG8 = (size_t)BC * Sn * Hn;       // BC * 2 MiB
  char* a1 = ws;
  char* a2 = ws + SEG8;
  char* b1 = ws + 2 * SEG8;
  char* b2 = ws + 3 * SEG8;
  char* memq = ws + 4 * SEG8;                     // 1 SEG8
  short* scores = (short*)(ws + 5 * SEG8);        // 4 SEG8 (BC x 8 MiB)

  for (int b0 = 0; b0 < Bn; b0 += BC) {
    const float* seqb = seq + (size_t)b0 * Sn * Hn;
    const float* memb = mem + (size_t)b0 * Nn * Hn;
    const int* mkb = mmask + (size_t)b0 * Nn;
    float* outb = out + (size_t)b0 * Sn * Hn;

    prep_seq_i8<<<dim3(BC * Sn * Hn / 4 / 256), 256, 0, stream>>>(seqb, a1, a2);
    prep_bt<<<dim3(Nn / 64, Hn / 32, BC), 256, 0, stream>>>(memb, mkb, b1, b2, memq);
    gemm_scores_coarse<<<dim3(Nn / 128, Sn / 128, BC), 256, 0, stream>>>(a1, b1, scores);
    softmax_attn<<<dim3(BC * Sn), 256, 0, stream>>>(scores, memq, b1, b2, a1, a2, outb);
  }
}

// Round 20
// 337.493 us; speedup vs baseline: 1.2613x; 1.0748x over previous
//
#include <hip/hip_runtime.h>
#include <cstdint>
#include <cstddef>

// Problem constants
#define Bn 16
#define Sn 2048
#define Hn 1024
#define Nn 2048   // n_examples * mem_len

typedef unsigned short u16;
typedef float  f32x4  __attribute__((ext_vector_type(4)));
typedef int    i32x4  __attribute__((ext_vector_type(4)));
typedef short  s16x8  __attribute__((ext_vector_type(8)));
typedef unsigned char  u8x4  __attribute__((ext_vector_type(4)));
typedef unsigned char  u8x8  __attribute__((ext_vector_type(8)));

// Two-level int8 quantization: x ~ (q1 + q2/128)/16, q1,q2 in [-127,127].
__device__ __forceinline__ void quant2(float x, char& q1, char& q2) {
  float f1 = rintf(x * 16.f);
  f1 = fminf(127.f, fmaxf(-127.f, f1));
  float r = x - f1 * 0.0625f;
  float f2 = rintf(r * 2048.f);
  f2 = fminf(127.f, fmaxf(-127.f, f2));
  q1 = (char)(int)f1;
  q2 = (char)(int)f2;
}

// Single-level i8 x16 (for the gather's mem operand; max err 1/32).
__device__ __forceinline__ char quant1(float x) {
  float f = rintf(x * 16.f);
  f = fminf(127.f, fmaxf(-127.f, f));
  return (char)(int)f;
}

// Stage 16 rows x 64B (one global_load_lds_dwordx4 per lane, LDS dest linear
// base + lane*16). Global source granule XOR-swizzled with (row>>1)&3 so the
// ds_read side (same XOR) is bank-conflict-free (both-sides rule #21).
__device__ __forceinline__ void stage64Bb(const char* gbase, int pitchBytes, void* ldsbase, int lane) {
  const int gsrc = (lane & 3) ^ ((lane >> 3) & 3);   // g ^ ((row_local>>1)&3), row_local = lane>>2
  const char* gp = gbase + (size_t)(lane >> 2) * pitchBytes + gsrc * 16;
  __builtin_amdgcn_global_load_lds(
      (__attribute__((address_space(1))) void*)gp,
      (__attribute__((address_space(3))) void*)ldsbase, 16, 0, 0);
}

// ---------------- prep kernels (batch-chunk local) ----------------

// seq fp32 -> two-level i8, 4 per thread.
__global__ __launch_bounds__(256) void prep_seq_i8(const float* __restrict__ seq,
                                                   char* __restrict__ a1, char* __restrict__ a2) {
  size_t i = (size_t)blockIdx.x * 256 + threadIdx.x;
  float4 v = ((const float4*)seq)[i];
  float x[4] = {v.x, v.y, v.z, v.w};
  u8x4 p1, p2;
#pragma unroll
  for (int j = 0; j < 4; ++j) {
    char q1, q2;
    quant2(x[j], q1, q2);
    p1[j] = (unsigned char)q1;
    p2[j] = (unsigned char)q2;
  }
  ((u8x4*)a1)[i] = p1;
  ((u8x4*)a2)[i] = p2;
}

// Fused memory prep: reads each mem element ONCE (as the [N][H] view), emits
//  bt1[n'][h'] i8 two-level  where flat[h'*2048+n'] = flat[r*1024+c]
//    (n' = (r&1)*1024 + c, h' = r>>1; mask index = 2h'+(n'>>10) = r)
//  memq[n][h]  i8 x16        (natural [N][H] layout, masked; gather operand)
__global__ __launch_bounds__(256) void prep_bt(const float* __restrict__ mem,
                                               const int* __restrict__ mmask,
                                               char* __restrict__ b1o, char* __restrict__ b2o,
                                               char* __restrict__ memq) {
  __shared__ float tile[64][33];
  const int b = blockIdx.z;
  const int r0 = blockIdx.x * 64;   // 32 blocks (n dim)
  const int c0 = blockIdx.y * 32;   // 32 blocks (h dim)
  const int tx = threadIdx.x & 31, ty = threadIdx.x >> 5;   // 32 x 8
  const float* src = mem + (size_t)b * (Nn * Hn);
  const int* mk = mmask + b * Nn;
#pragma unroll
  for (int j = 0; j < 8; ++j) {
    int r = r0 + ty + j * 8;
    float v = src[(size_t)r * Hn + c0 + tx];
    v = mk[r] ? v : 0.f;
    tile[ty + j * 8][tx] = v;
  }
  __syncthreads();
  // memq: natural layout; 4 threads per n-row, 8 i8 each (32B/row region).
  {
    const int nr = threadIdx.x >> 2;          // 0..63 (n local)
    const int hb = (threadIdx.x & 3) * 8;     // 0..24 (h local)
    u8x8 ov;
#pragma unroll
    for (int j = 0; j < 8; ++j) ov[j] = (unsigned char)quant1(tile[nr][hb + j]);
    *(u8x8*)(memq + (size_t)b * Nn * Hn + (size_t)(r0 + nr) * Hn + c0 + hb) = ov;
  }
  // bt1: n' = p*1024 + c0 + cl, h' = r0/2 + q*8 + j; 8 i8 pairs per thread
  {
    const int cl = threadIdx.x & 31;
    const int p  = (threadIdx.x >> 5) & 1;
    const int q  = threadIdx.x >> 6;          // 0..3
    u8x8 o1, o2;
#pragma unroll
    for (int j = 0; j < 8; ++j) {
      char q1, q2;
      quant2(tile[2 * (q * 8 + j) + p][cl], q1, q2);
      o1[j] = (unsigned char)q1;
      o2[j] = (unsigned char)q2;
    }
    size_t o = (size_t)b * Nn * Hn + (size_t)(p * 1024 + c0 + cl) * Hn + (r0 >> 1) + q * 8;
    *(u8x8*)(b1o + o) = o1;
    *(u8x8*)(b2o + o) = o2;
  }
}

// ---------------- GEMM1 (coarse): scores_c = a1.b1/256, i16 x128 ----------------
// 128x128 tile, BK=64, 4 waves (2x2). TRI-buffered LDS (3 x 16KB = 48KB,
// 3 blocks/CU), stage(k+2) issued in body k, counted vmcnt(4) entry waits.
__global__ __launch_bounds__(256, 3) void gemm_scores_coarse(
    const char* __restrict__ A1, const char* __restrict__ B1,
    short* __restrict__ C) {
  __shared__ __align__(16) char ldsm[49152];   // 3 buffers x {A 8KB | B 8KB}
  const int b = blockIdx.z;
  // XCD-aware remap: each XCD's blocks form an 8(tn) x 4(tm) rectangle.
  const int lid = blockIdx.x + (blockIdx.y << 4);
  const int xcd = lid & 7, idx = lid >> 3;
  const int tn = ((xcd & 1) << 3) | (idx & 7);
  const int tm = ((xcd >> 1) << 2) | (idx >> 3);
  const int tid = threadIdx.x;
  const int w = tid >> 6, l = tid & 63;
  const int wr = w >> 1, wc = w & 1;
  const size_t aOff = (size_t)(b * Sn + tm * 128) * Hn;
  const size_t bOff = (size_t)(b * Nn + tn * 128) * Hn;

  i32x4 acc[4][4] = {};

  const int gRd = ((l >> 4) ^ ((l >> 1) & 3)) * 16;
  const int ao = (wr * 64 + (l & 15)) * 64 + gRd;
  const int bo = (wc * 64 + (l & 15)) * 64 + gRd;

  auto stageStep = [&](int kk, char* buf) {   // 4 loads per lane
    const int kb = kk * 64;
#pragma unroll
    for (int i = 0; i < 2; ++i) {
      const int rb = w * 32 + i * 16;
      const size_t ro = (size_t)rb * Hn + kb;
      stage64Bb(A1 + aOff + ro, Hn, buf + rb * 64, l);
      stage64Bb(B1 + bOff + ro, Hn, buf + 8192 + rb * 64, l);
    }
  };

  stageStep(0, ldsm);
  stageStep(1, ldsm + 16384);

  int cb = 0;
  for (int kk = 0; kk < 16; ++kk) {
    char* cur = ldsm + cb * 16384;
    int sb = cb + 2; if (sb >= 3) sb -= 3;
    if (kk <= 14) asm volatile("s_waitcnt vmcnt(4)" ::: "memory");
    else          asm volatile("s_waitcnt vmcnt(0)" ::: "memory");
    __builtin_amdgcn_s_barrier();
    asm volatile("" ::: "memory");
    __builtin_amdgcn_sched_barrier(0);
    i32x4 bfr[4];
#pragma unroll
    for (int ni = 0; ni < 4; ++ni) bfr[ni] = *(const i32x4*)(cur + 8192 + bo + ni * 1024);
    i32x4 afr[4];
#pragma unroll
    for (int mi = 0; mi < 4; ++mi) afr[mi] = *(const i32x4*)(cur + ao + mi * 1024);
    if (kk + 2 < 16) stageStep(kk + 2, ldsm + sb * 16384);
    __builtin_amdgcn_s_setprio(1);
#pragma unroll
    for (int mi = 0; mi < 4; ++mi)
#pragma unroll
      for (int ni = 0; ni < 4; ++ni)
        acc[mi][ni] = __builtin_amdgcn_mfma_i32_16x16x64_i8(afr[mi], bfr[ni], acc[mi][ni], 0, 0, 0);
    __builtin_amdgcn_s_setprio(0);
    cb = (cb + 1 == 3) ? 0 : cb + 1;
  }
  // coarse_fixed = acc/2 (= coarse_score * 128), i16.
  const int r0 = tm * 128 + wr * 64 + (l >> 4) * 4;
  const int c0 = tn * 128 + wc * 64 + (l & 15);
#pragma unroll
  for (int mi = 0; mi < 4; ++mi)
#pragma unroll
    for (int ni = 0; ni < 4; ++ni) {
      size_t base = (size_t)(b * Sn + r0 + mi * 16) * Nn + c0 + ni * 16;
#pragma unroll
      for (int j = 0; j < 4; ++j) {
        int s = (int)rintf((float)acc[mi][ni][j] * 0.5f);
        s = s > 32767 ? 32767 : (s < -32767 ? -32767 : s);
        C[base + (size_t)j * Nn] = (short)s;
      }
    }
}

// ---------------- Fused softmax + refinement + sparse gather + residual ----------------
// WAVE-PER-ROW: each 64-lane wave independently handles one output row (4
// rows per 256-block), NO __syncthreads anywhere -- within-wave LDS RAW is
// ordered by the compiler's lgkmcnt insertion. Same candidate SET/threshold
// as R15/R19 (extraction order is lane-major -> only last-ulp float-sum
// differences; gather is exact i32). Deterministic (no atomics, fixed order).
__global__ __launch_bounds__(256) void softmax_attn(
    const short* __restrict__ sc,    // i16 coarse scores x128, [BC*Sn][Nn]
    const char* __restrict__ memq,   // i8 mem x16, [BC][Nn][Hn]
    const char* __restrict__ B1q, const char* __restrict__ B2q,  // bt1 two-level
    const char* __restrict__ A1q, const char* __restrict__ A2q,
    float* __restrict__ out) {
  __shared__ unsigned short sidxS[4][64];
  __shared__ int scandS[4][64];
  __shared__ int scrossS[4][64];
  __shared__ unsigned char spS[4][64];
  const int t = threadIdx.x;
  const int w = t >> 6, l = t & 63;
  const size_t row = (size_t)blockIdx.x * 4 + w;
  const int b = (int)(row >> 11);          // Sn = 2048 rows per batch
  unsigned short* sidx = sidxS[w];
  int* scand = scandS[w];
  int* scross = scrossS[w];
  unsigned char* sp = spS[w];

  // Load 32 entries/lane: chunk j covers entries j*512 + l*8 .. +7 (coalesced).
  const short* prow = sc + row * Nn;
  s16x8 v[4];
#pragma unroll
  for (int j = 0; j < 4; ++j) v[j] = *(const s16x8*)(prow + j * 512 + l * 8);
  int mymax = (int)v[0][0];
#pragma unroll
  for (int j = 0; j < 4; ++j)
#pragma unroll
    for (int e = 0; e < 8; ++e) mymax = max(mymax, (int)v[j][e]);
  for (int o = 32; o > 0; o >>= 1) mymax = max(mymax, __shfl_xor(mymax, o));
  const int thresh = mymax - 1408;         // 11 * 128
  // count + wave exclusive scan
  int cnt = 0;
#pragma unroll
  for (int j = 0; j < 4; ++j)
#pragma unroll
    for (int e = 0; e < 8; ++e) cnt += ((int)v[j][e] >= thresh);
  int incl = cnt;
  for (int o = 1; o < 64; o <<= 1) {
    int xv = __shfl_up(incl, o);
    if (l >= o) incl += xv;
  }
  int total = __shfl(incl, 63);
  if (total > 64) total = 64;
  int pos = incl - cnt;
#pragma unroll
  for (int j = 0; j < 4; ++j)
#pragma unroll
    for (int e = 0; e < 8; ++e)
      if ((int)v[j][e] >= thresh) {
        if (pos < 64) { sidx[pos] = (unsigned short)(j * 512 + l * 8 + e); scand[pos] = (int)v[j][e]; }
        pos++;
      }
  // Refinement: wave-serial over candidates (typically 1-3); lane l covers
  // the 16-byte k-slice at l*16 of the 1024-wide dot.
  const i32x4 a1s = *(const i32x4*)(A1q + row * (size_t)Hn + l * 16);
  const i32x4 a2s = *(const i32x4*)(A2q + row * (size_t)Hn + l * 16);
  for (int k = 0; k < total; ++k) {
    const size_t nb = ((size_t)b * Nn + sidx[k]) * Hn + l * 16;
    const i32x4 b1v = *(const i32x4*)(B1q + nb);
    const i32x4 b2v = *(const i32x4*)(B2q + nb);
    int cross = 0;
#pragma unroll
    for (int r = 0; r < 4; ++r)
#pragma unroll
      for (int s8 = 0; s8 < 4; ++s8) {
        const int sh = s8 * 8;
        cross += (int)(char)(a1s[r] >> sh) * (int)(char)(b2v[r] >> sh)
               + (int)(char)(a2s[r] >> sh) * (int)(char)(b1v[r] >> sh);
      }
    for (int o = 32; o > 0; o >>= 1) cross += __shfl_xor(cross, o);
    if (l == 0) scross[k] = cross;
  }
  // p8 over refined candidates (lanes 0..total-1)
  if (l < total) {
    float mref = -1e30f;
    for (int k = 0; k < total; ++k) {
      float f = (float)scand[k] * 0.0078125f + (float)scross[k] * (1.f / 32768.f);
      mref = fmaxf(mref, f);
    }
    float s = 0.f;
    for (int k = 0; k < total; ++k) {
      float f = (float)scand[k] * 0.0078125f + (float)scross[k] * (1.f / 32768.f);
      s += __expf(f - mref);
    }
    const float fme = (float)scand[l] * 0.0078125f + (float)scross[l] * (1.f / 32768.f);
    sp[l] = (unsigned char)(int)rintf(127.f * __expf(fme - mref) / s);
  }
  // Gather: lane l owns h = c*256 + l*4 (c=0..3); per candidate 4 coalesced
  // dword reads (256B/instruction); exact i32 accumulate.
  const char* mq = memq + (size_t)b * (Nn * Hn);
  int accv[4][4] = {};
  for (int k = 0; k < total; ++k) {
    const int pw = sp[k];
    if (!pw) continue;
    const char* mrow = mq + (size_t)sidx[k] * Hn;
#pragma unroll
    for (int c = 0; c < 4; ++c) {
      const int wv = *(const int*)(mrow + c * 256 + l * 4);
#pragma unroll
      for (int e = 0; e < 4; ++e)
        accv[c][e] += pw * (int)(char)(wv >> (e * 8));
    }
  }
  // Residual from a1/a2 (seq ~ a1/16 + a2/2048) + acc/(127*16); coalesced
  // float4 writes (lane stride 16B within each 1KB chunk).
  const float scl = 1.f / 2032.f;
#pragma unroll
  for (int c = 0; c < 4; ++c) {
    const size_t hb = (size_t)c * 256 + l * 4;
    const int w1 = *(const int*)(A1q + row * (size_t)Hn + hb);
    const int w2 = *(const int*)(A2q + row * (size_t)Hn + hb);
    float4 o;
    o.x = (float)(char)(w1)       * 0.0625f + (float)(char)(w2)       * (1.f / 2048.f) + (float)accv[c][0] * scl;
    o.y = (float)(char)(w1 >> 8)  * 0.0625f + (float)(char)(w2 >> 8)  * (1.f / 2048.f) + (float)accv[c][1] * scl;
    o.z = (float)(char)(w1 >> 16) * 0.0625f + (float)(char)(w2 >> 16) * (1.f / 2048.f) + (float)accv[c][2] * scl;
    o.w = (float)(char)(w1 >> 24) * 0.0625f + (float)(char)(w2 >> 24) * (1.f / 2048.f) + (float)accv[c][3] * scl;
    *(float4*)(out + row * Hn + hb) = o;
  }
}

// Distinctive fill if ws is too small: absmax ~12345 tells us it was this guard.
__global__ void ws_fail(float* out) {
  size_t i = (size_t)blockIdx.x * blockDim.x + threadIdx.x;
  size_t stride = (size_t)gridDim.x * blockDim.x;
  for (; i < (size_t)Bn * Sn * Hn; i += stride) out[i] = 12345.0f;
}

extern "C" void kernel_launch(void* const* d_in, const int* in_sizes, int n_in,
                              void* d_out, int out_size, void* d_ws, size_t ws_size,
                              hipStream_t stream) {
  const float* seq = (const float*)d_in[0];
  // d_in[1] (attention_mask) is unused by the reference
  const float* mem = (const float*)d_in[2];
  const int* mmask = (const int*)d_in[3];
  float* out = (float*)d_out;

  // Per-batch: a1,a2,b1,b2 (4x2 MiB) + memq (2 MiB) + scores i16 (8 MiB) = 18 MiB
  const size_t MiB = 1024 * 1024;
  const size_t perB = 18 * MiB;
  int BC = 16;
  while (BC > 1 && (size_t)BC * perB > ws_size) BC >>= 1;
  if ((size_t)BC * perB > ws_size) {
    ws_fail<<<2048, 256, 0, stream>>>(out);
    return;
  }

  char* ws = (char*)d_ws;
  const size_t SEG8 = (size_t)BC * Sn * Hn;       // BC * 2 MiB
  char* a1 = ws;
  char* a2 = ws + SEG8;
  char* b1 = ws + 2 * SEG8;
  char* b2 = ws + 3 * SEG8;
  char* memq = ws + 4 * SEG8;                     // 1 SEG8
  short* scores = (short*)(ws + 5 * SEG8);        // 4 SEG8 (BC x 8 MiB)

  for (int b0 = 0; b0 < Bn; b0 += BC) {
    const float* seqb = seq + (size_t)b0 * Sn * Hn;
    const float* memb = mem + (size_t)b0 * Nn * Hn;
    const int* mkb = mmask + (size_t)b0 * Nn;
    float* outb = out + (size_t)b0 * Sn * Hn;

    prep_seq_i8<<<dim3(BC * Sn * Hn / 4 / 256), 256, 0, stream>>>(seqb, a1, a2);
    prep_bt<<<dim3(Nn / 64, Hn / 32, BC), 256, 0, stream>>>(memb, mkb, b1, b2, memq);
    gemm_scores_coarse<<<dim3(Nn / 128, Sn / 128, BC), 256, 0, stream>>>(a1, b1, scores);
    softmax_attn<<<dim3(BC * Sn / 4), 256, 0, stream>>>(scores, memq, b1, b2, a1, a2, outb);
  }
}